// Round 12
// baseline (109.244 us; speedup 1.0000x reference)
//
#include <hip/hip_runtime.h>
#include <hip/hip_bf16.h>

#define S49 49
#define D128 128
#define NH 4

typedef __attribute__((ext_vector_type(8))) short short8;
typedef __attribute__((ext_vector_type(4))) float f32x4;

__device__ __forceinline__ unsigned short f2b(float x){
  unsigned u = __builtin_bit_cast(unsigned, x);
  return (unsigned short)((u + 0x7fffu + ((u>>16)&1u)) >> 16);   // RNE
}
__device__ __forceinline__ unsigned pk2(float a, float b){
  __hip_bfloat162 h = __float22bfloat162_rn(float2{a, b});      // HW v_cvt_pk_bf16_f32
  unsigned u; __builtin_memcpy(&u, &h, 4);
  return u;
}
// XOR-swizzled LDS indexing (ushort units), 16B granule: conflict-free
// fragment reads at power-of-2 strides, no padding.
__device__ __forceinline__ int swz256i(int row, int col){  // 128-elem (256B) rows
  return row*128 + ((((col>>3) ^ (row&15)) << 3) | (col&7));
}

// ---- K0: transpose weights to Wt[mat][n][k] bf16 in workspace ----
__global__ void prep_wt(const float* __restrict__ Wq, const float* __restrict__ Wk,
                        const float* __restrict__ Wv, unsigned short* __restrict__ wt){
  int e = blockIdx.x*256 + threadIdx.x;
  if (e >= 3*128*128) return;
  int mat = e >> 14, rem = e & 16383, n = rem >> 7, k = rem & 127;
  const float* W = (mat==0) ? Wq : ((mat==1) ? Wk : Wv);
  wt[e] = f2b(W[k*128 + n]);
}

// ---- K1: combined (mask + rel-pos-bias) table for the S^T lane layout ----
// comb4[(((w*NH+h)*49)+i)*16 + nt*4 + lg] = { c(i, 16nt+4lg+r) for r=0..3 } * log2e
// c(i,j) = mask[w][i][j] + bias_table[idx(i,j)][h]; pad j>=49 -> -1e30 (exp2 -> 0).
__global__ void prep_comb(const float* __restrict__ mask, const float* __restrict__ bt,
                          float4* __restrict__ comb4, int nW){
  int e = blockIdx.x*256 + threadIdx.x;
  if (e >= nW*NH*S49*16) return;
  int s = e & 15; int nt = s >> 2, lg = s & 3;
  int t = e >> 4;
  int i = t % S49; t /= S49;
  int h = t & (NH-1); int w = t / NH;
  const float* mrow = mask + ((size_t)w*S49 + i)*S49;
  int ri = i/7, ci = i - ri*7;
  const float L2E = 1.4426950408889634f;
  float v[4];
  #pragma unroll
  for (int r = 0; r < 4; ++r){
    int j = nt*16 + lg*4 + r;
    if (j < S49){
      int rj = j/7, cj = j - rj*7;
      int idx = (ri - rj + 6)*13 + (ci - cj + 6);
      v[r] = (mrow[j] + bt[idx*NH + h]) * L2E;
    } else v[r] = -1e30f;
  }
  float4 o; o.x = v[0]; o.y = v[1]; o.z = v[2]; o.w = v[3];
  comb4[e] = o;
}

// ---- main fused kernel: one block (8 waves) per window, 2 barriers, 3 blocks/CU ----
// wave = (row-tile rt = wave&3, head-pair hp = wave>>2). Swapped QK^T (S^T =
// mfma(K,Q)) makes softmax lane-local: lane holds q-row=ln, k=16nt+4lg+r.
__global__ __launch_bounds__(512, 6) void swin_attn(
    const float* __restrict__ hs,
    const float* __restrict__ bq, const float* __restrict__ bk,
    const float* __restrict__ bv,
    const float4* __restrict__ comb4,
    const unsigned short* __restrict__ wt, float* __restrict__ out, int nW){

  // 53760 B: hs/P 12544 | q 12544 | k 12544 | vt 14336 | pext 1792
  __shared__ __align__(16) unsigned short lds[26880];
  unsigned short* hs_s = lds;              // 49x128 swz256i; dead after proj -> P tiles waves 0..6
  unsigned short* q_s  = lds + 6272;       // 49x128 swz256i
  unsigned short* k_s  = lds + 12544;      // 49x128 swz256i (QK tile-3 rows reg-masked)
  unsigned short* vt_s = lds + 18816;      // 128x56 LINEAR (cols 49..55 zeroed)
  unsigned short* pext = lds + 25984;      // wave 7's P tile (16x56)

  const int b = blockIdx.x;
  const int tid = threadIdx.x;
  const int wave = tid >> 6, lane = tid & 63;
  const int lg = lane >> 4, ln = lane & 15;
  unsigned short* pp = (wave < 7) ? (hs_s + wave*896) : pext;   // 16x56 normalized-P per wave

  // ---- stage hidden_states f32 -> bf16 LDS ----
  const float* hsb = hs + (size_t)b * (S49*D128);
  #pragma unroll
  for (int it = 0; it < 4; ++it) {
    int u = tid + it*512;                  // 1568 units of 4 f32
    if (u < S49*32) {
      int row = u >> 5, c = u & 31;
      float4 f = *(const float4*)(hsb + row*128 + c*4);
      uint2 o; o.x = pk2(f.x, f.y); o.y = pk2(f.z, f.w);
      *(uint2*)&hs_s[swz256i(row, c*4)] = o;
    }
  }
  // zero vt cols 48..55 with two 8B stores per row (col 48 rewritten by projection)
  if (tid < 128) {
    uint2 z2 = {0u,0u};
    *(uint2*)&vt_s[tid*56 + 48] = z2;
    *(uint2*)&vt_s[tid*56 + 52] = z2;
  }
  __syncthreads();

  const int w = b % nW;
  const int rt = wave & 3, hp = wave >> 2;
  const int mbw = (rt<3) ? rt*16 : 33;     // wave's q-row tile (overlap rows recompute identically)

  // ---- QKV projection: wave owns 16 output cols; Q,K,V processed sequentially ----
  {
    const int ntb = wave*16;
    #pragma unroll 1
    for (int mat = 0; mat < 3; ++mat) {
      short8 a[4];
      #pragma unroll
      for (int ks = 0; ks < 4; ++ks)
        a[ks] = *(const short8*)&wt[(mat<<14) + (ntb+ln)*128 + ks*32 + lg*8];
      const float* bp = (mat==0) ? bq : ((mat==1) ? bk : bv);
      float4 bias = *(const float4*)&bp[ntb + 4*lg];
      #pragma unroll
      for (int mt = 0; mt < 4; ++mt) {
        const int mb = (mt<3) ? mt*16 : 33;      // overlapping tiles cover rows 0..48
        short8 bh[4];
        #pragma unroll
        for (int ks = 0; ks < 4; ++ks)
          bh[ks] = *(const short8*)&hs_s[swz256i(mb+ln, ks*32 + lg*8)];
        f32x4 acc = {0.f,0.f,0.f,0.f};
        #pragma unroll
        for (int ks = 0; ks < 4; ++ks)
          acc = __builtin_amdgcn_mfma_f32_16x16x32_bf16(a[ks], bh[ks], acc, 0,0,0);
        // D transposed: col(ln) = token row m, rows(4lg+r) = output col n
        const int m = mb + ln;
        const int nb = ntb + 4*lg;
        if (mat == 0) {
          uint2 o; o.x = pk2(acc[0]+bias.x, acc[1]+bias.y);
                   o.y = pk2(acc[2]+bias.z, acc[3]+bias.w);
          *(uint2*)&q_s[swz256i(m, nb)] = o;
        } else if (mat == 1) {
          uint2 o; o.x = pk2(acc[0]+bias.x, acc[1]+bias.y);
                   o.y = pk2(acc[2]+bias.z, acc[3]+bias.w);
          *(uint2*)&k_s[swz256i(m, nb)] = o;
        } else {
          vt_s[(nb+0)*56 + m] = f2b(acc[0]+bias.x);
          vt_s[(nb+1)*56 + m] = f2b(acc[1]+bias.y);
          vt_s[(nb+2)*56 + m] = f2b(acc[2]+bias.z);
          vt_s[(nb+3)*56 + m] = f2b(acc[3]+bias.w);
        }
      }
    }
  }
  __syncthreads();
  // ---- attention: NO barriers (P wave-private; q/k/vt read-only; pp aliases dead hs) ----

  const float C1 = 0.17677669529663687f * 1.4426950408889634f;  // scale * log2e
  const short8 z8 = {0,0,0,0,0,0,0,0};

  #pragma unroll
  for (int hh = 0; hh < 2; ++hh) {
    const int h = hp*2 + hh;
    // combined bias+mask for S^T lane layout: lane needs c(q=mbw+ln, k=16nt+4lg+r)
    float4 cb[4];
    #pragma unroll
    for (int nt = 0; nt < 4; ++nt)
      cb[nt] = comb4[((size_t)((w*NH + h)*S49) + mbw + ln)*16 + nt*4 + lg];

    // ---- S^T = mfma(K, Q): lane holds q=ln, k=16nt+4lg+r ----
    short8 aq = *(const short8*)&q_s[swz256i(mbw+ln, h*32 + lg*8)];
    short8 kb[4];
    #pragma unroll
    for (int nt = 0; nt < 4; ++nt)
      kb[nt] = *(const short8*)&k_s[swz256i(nt*16+ln, h*32 + lg*8)];  // nt=3 ln>0: garbage rows
    if (ln != 0) kb[3] = z8;                                          // only k-row 48 is real
    f32x4 st[4];
    __builtin_amdgcn_s_setprio(1);
    #pragma unroll
    for (int nt = 0; nt < 4; ++nt) {
      f32x4 z = {0.f,0.f,0.f,0.f};
      st[nt] = __builtin_amdgcn_mfma_f32_16x16x32_bf16(kb[nt], aq, z, 0,0,0);
    }
    __builtin_amdgcn_s_setprio(0);

    // ---- lane-local max-free softmax: exp, tree-sum, 2 shfl, rcp ----
    float e[4][4], psum[4];
    #pragma unroll
    for (int nt = 0; nt < 4; ++nt) {
      float cbv[4] = {cb[nt].x, cb[nt].y, cb[nt].z, cb[nt].w};
      #pragma unroll
      for (int r = 0; r < 4; ++r)
        e[nt][r] = __builtin_amdgcn_exp2f(fmaf(st[nt][r], C1, cbv[r]));
      psum[nt] = (e[nt][0] + e[nt][1]) + (e[nt][2] + e[nt][3]);
    }
    float sum = (psum[0] + psum[1]) + (psum[2] + psum[3]);
    sum += __shfl_xor(sum, 16, 64);
    sum += __shfl_xor(sum, 32, 64);
    const float inv = __builtin_amdgcn_rcpf(sum);

    // ---- normalized P -> LDS row q=ln (8 aligned u32 writes; k=16nt+4lg+2rp) ----
    #pragma unroll
    for (int nt = 0; nt < 4; ++nt) {
      #pragma unroll
      for (int rp = 0; rp < 2; ++rp) {
        if (nt < 3 || lg < 2) {                    // row width 56: skip k>=56 slots
          unsigned u = pk2(e[nt][2*rp]*inv, e[nt][2*rp+1]*inv);
          *(unsigned*)&pp[ln*56 + nt*16 + lg*4 + 2*rp] = u;
        }
      }
    }

    // ---- PV: A = P rows (lane ln), B = V^T; output D = [q=4lg+r][d=ln] ----
    short8 ap0 = *(const short8*)&pp[ln*56 + lg*8];
    short8 ap1 = z8;
    if (lg < 3) ap1 = *(const short8*)&pp[ln*56 + 32 + lg*8];  // lg=3: k56-63 not stored
    #pragma unroll
    for (int nt = 0; nt < 2; ++nt) {
      const int vr = h*32 + nt*16 + ln;             // output col == vt row
      short8 bv0 = *(const short8*)&vt_s[vr*56 + lg*8];
      short8 bv1 = z8;
      if (lg < 3) bv1 = *(const short8*)&vt_s[vr*56 + 32 + lg*8];
      f32x4 acc = {0.f,0.f,0.f,0.f};
      __builtin_amdgcn_s_setprio(1);
      acc = __builtin_amdgcn_mfma_f32_16x16x32_bf16(ap0, bv0, acc, 0,0,0);
      acc = __builtin_amdgcn_mfma_f32_16x16x32_bf16(ap1, bv1, acc, 0,0,0);
      __builtin_amdgcn_s_setprio(0);
      const int mr = mbw + 4*lg;
      #pragma unroll
      for (int r = 0; r < 4; ++r)
        out[((size_t)b*S49 + mr + r)*D128 + vr] = acc[r];
    }
  }
}

extern "C" void kernel_launch(void* const* d_in, const int* in_sizes, int n_in,
                              void* d_out, int out_size, void* d_ws, size_t ws_size,
                              hipStream_t stream){
  const float* hs  = (const float*)d_in[0];
  const float* msk = (const float*)d_in[1];
  const float* Wq  = (const float*)d_in[2];
  const float* bq  = (const float*)d_in[3];
  const float* Wk  = (const float*)d_in[4];
  const float* bk  = (const float*)d_in[5];
  const float* Wv  = (const float*)d_in[6];
  const float* bv  = (const float*)d_in[7];
  const float* bt  = (const float*)d_in[8];
  unsigned short* wt = (unsigned short*)d_ws;
  float4* comb4 = (float4*)((char*)d_ws + 98304);
  float* out = (float*)d_out;
  const int B  = in_sizes[0] / (S49*D128);
  const int nW = in_sizes[1] / (S49*S49);
  prep_wt<<<dim3((3*128*128 + 255)/256), dim3(256), 0, stream>>>(Wq, Wk, Wv, wt);
  prep_comb<<<dim3((nW*NH*S49*16 + 255)/256), dim3(256), 0, stream>>>(msk, bt, comb4, nW);
  swin_attn<<<dim3(B), dim3(512), 0, stream>>>(hs, bq, bk, bv, comb4, wt, out, nW);
}